// Round 1
// baseline (734.289 us; speedup 1.0000x reference)
//
#include <hip/hip_runtime.h>
#include <math.h>

// LocalDiffusionInteractionBlock — round 1: correct fp32 baseline.
// Phase 1 (node_kernel): node_scalars / s_up / v_up  (5 small GEMMs, scalar-load rows)
// Phase 2 (edge_kernel): wave = 4 edges; wi build + switch_norm + MLP via
//   transposed LDS tiles (one ds_read_b128 serves 4 edges per k), then
//   m0/m1 + atomicAdd scatter into M0 (N,256) / M1 (N,3,256).
// Phase 3 (out_kernel): o0/o1 GEMMs + interleaved float4 store (N,128,4).

#define PI_F 3.14159265358979323846f
#define WPB 4   // waves per block (edge kernel)
#define EPW 4   // edges per wave

static __device__ __forceinline__ float silu_f(float x) {
  return x / (1.0f + __expf(-x));
}

// ---------------------------------------------------------------- node kernel
__global__ __launch_bounds__(64)
void node_kernel(const float* __restrict__ nf,
                 const float* __restrict__ Ws,
                 const float* __restrict__ Wu0,
                 const float* __restrict__ Wu1,
                 float* __restrict__ ns, float* __restrict__ su,
                 float* __restrict__ vu, int N)
{
  const int lane = threadIdx.x;            // 64 lanes; outputs o = lane, lane+64
  const int n0 = blockIdx.x * 4;
  float a_ns[4][2] = {}, a_su[4][2] = {}, a_vu[4][3][2] = {};
  const float* row[4];
#pragma unroll
  for (int i = 0; i < 4; i++) {
    int n = n0 + i; if (n >= N) n = N - 1;
    row[i] = nf + (size_t)n * 512;
  }
  for (int u = 0; u < 128; ++u) {
    float ws0 = Ws[u * 128 + lane],  ws1 = Ws[u * 128 + 64 + lane];
    float wa0 = Wu0[u * 128 + lane], wa1 = Wu0[u * 128 + 64 + lane];
    float wb0 = Wu1[u * 128 + lane], wb1 = Wu1[u * 128 + 64 + lane];
#pragma unroll
    for (int i = 0; i < 4; i++) {
      float s = row[i][u];
      a_ns[i][0] = fmaf(s, ws0, a_ns[i][0]); a_ns[i][1] = fmaf(s, ws1, a_ns[i][1]);
      a_su[i][0] = fmaf(s, wa0, a_su[i][0]); a_su[i][1] = fmaf(s, wa1, a_su[i][1]);
      float vx = row[i][128 + u * 3 + 0];
      float vy = row[i][128 + u * 3 + 1];
      float vz = row[i][128 + u * 3 + 2];
      a_vu[i][0][0] = fmaf(vx, wb0, a_vu[i][0][0]); a_vu[i][0][1] = fmaf(vx, wb1, a_vu[i][0][1]);
      a_vu[i][1][0] = fmaf(vy, wb0, a_vu[i][1][0]); a_vu[i][1][1] = fmaf(vy, wb1, a_vu[i][1][1]);
      a_vu[i][2][0] = fmaf(vz, wb0, a_vu[i][2][0]); a_vu[i][2][1] = fmaf(vz, wb1, a_vu[i][2][1]);
    }
  }
  const float inv = 1.0f / sqrtf(128.0f);
#pragma unroll
  for (int i = 0; i < 4; i++) {
    int n = n0 + i;
    if (n >= N) break;
    ns[(size_t)n * 128 + lane]      = a_ns[i][0] * inv;
    ns[(size_t)n * 128 + 64 + lane] = a_ns[i][1] * inv;
    su[(size_t)n * 128 + lane]      = a_su[i][0] * inv;
    su[(size_t)n * 128 + 64 + lane] = a_su[i][1] * inv;
#pragma unroll
    for (int d = 0; d < 3; d++) {
      vu[((size_t)n * 3 + d) * 128 + lane]      = a_vu[i][d][0] * inv;
      vu[((size_t)n * 3 + d) * 128 + 64 + lane] = a_vu[i][d][1] * inv;
    }
  }
}

// ---------------------------------------------------------------- edge kernel
__global__ __launch_bounds__(256)
void edge_kernel(const float* __restrict__ eattr,
                 const float* __restrict__ elen,
                 const float* __restrict__ tdif,
                 const float* __restrict__ lens,
                 const int*   __restrict__ eidx,
                 const float* __restrict__ snw, const float* __restrict__ snb,
                 const float* __restrict__ snmw, const float* __restrict__ snvw,
                 const float* __restrict__ snrm, const float* __restrict__ snrv,
                 const float* __restrict__ W1, const float* __restrict__ W2,
                 const float* __restrict__ W3, const float* __restrict__ W4,
                 const float* __restrict__ ns, const float* __restrict__ su,
                 const float* __restrict__ vu,
                 float* __restrict__ M0, float* __restrict__ M1,
                 int E)
{
  // transposed tiles: [k][edge] so one b128 read broadcasts 4 edges at one k
  __shared__ __align__(16) float wi_t[WPB][265][4];
  __shared__ __align__(16) float hA[WPB][64][4];
  __shared__ __align__(16) float hB[WPB][64][4];

  const int lane = threadIdx.x & 63;
  const int wave = threadIdx.x >> 6;
  const int ebase = blockIdx.x * (WPB * EPW) + wave * EPW;

  int snd[EPW], rcv[EPW];
  float cutf[EPW], y0v[EPW], y1v[EPW][3], rr[EPW], ttv[EPW], lnv[EPW];
  bool valid[EPW];
#pragma unroll
  for (int i = 0; i < EPW; i++) {
    int e = ebase + i;
    valid[i] = (e < E);
    if (!valid[i]) e = E - 1;
    snd[i] = eidx[e]; rcv[i] = eidx[E + e];
    float r = elen[e]; rr[i] = r; ttv[i] = tdif[e]; lnv[i] = lens[e];
    float u = r * 0.2f;
    float u2 = u * u, u4 = u2 * u2, u5 = u4 * u;
    float c = 1.0f - 21.0f * u5 + 35.0f * u5 * u - 15.0f * u5 * u2;
    cutf[i] = (u < 1.0f) ? c : 0.0f;
    y0v[i] = eattr[e * 4 + 0];
    y1v[i][0] = eattr[e * 4 + 1];
    y1v[i][1] = eattr[e * 4 + 2];
    y1v[i][2] = eattr[e * 4 + 3];
  }

  // ---- build wi (raw) + accumulate per-edge sum / sumsq ----
  float s1[EPW] = {}, s2[EPW] = {};
#pragma unroll
  for (int q = 0; q < 4; q++) {
    const int ii = lane + q * 64;
    const int col = ii & 127;
#pragma unroll
    for (int i = 0; i < EPW; i++) {
      int nrow = (q < 2) ? snd[i] : rcv[i];
      float v = ns[(size_t)nrow * 128 + col] * cutf[i];
      wi_t[wave][ii][i] = v;
      s1[i] += v; s2[i] += v * v;
    }
  }
  if (lane < 8) {                       // bessel features
    float kk = (float)(lane + 1) * (PI_F / 5.0f);
    const float pref = sqrtf(0.4f);
#pragma unroll
    for (int i = 0; i < EPW; i++) {
      float v = pref * __sinf(kk * rr[i]) / rr[i] * __expf(-kk * kk * ttv[i]) * cutf[i];
      wi_t[wave][256 + lane][i] = v;
      s1[i] += v; s2[i] += v * v;
    }
  } else if (lane == 8) {               // length feature
#pragma unroll
    for (int i = 0; i < EPW; i++) {
      float v = lnv[i] * cutf[i];
      wi_t[wave][264][i] = v;
      s1[i] += v; s2[i] += v * v;
    }
  }
  // wave-wide butterfly reduce (64 lanes)
#pragma unroll
  for (int i = 0; i < EPW; i++) {
    float a = s1[i], b = s2[i];
#pragma unroll
    for (int off = 32; off > 0; off >>= 1) {
      a += __shfl_xor(a, off);
      b += __shfl_xor(b, off);
    }
    s1[i] = a; s2[i] = b;
  }
  float mean_[EPW], var_[EPW];
#pragma unroll
  for (int i = 0; i < EPW; i++) {
    float m = s1[i] * (1.0f / 265.0f);
    mean_[i] = m;
    var_[i] = (s2[i] - s1[i] * m) * (1.0f / 264.0f);   // ddof=1
  }
  // switch-norm mixing weights (softmax over 2)
  float msm0 = 1.0f / (1.0f + __expf(snmw[1] - snmw[0])), msm1 = 1.0f - msm0;
  float vsm0 = 1.0f / (1.0f + __expf(snvw[1] - snvw[0])), vsm1 = 1.0f - vsm0;

  // normalize in place (each lane rewrites only its own entries)
#pragma unroll
  for (int q = 0; q < 5; q++) {
    const int ii = lane + q * 64;
    if (ii < 265) {
      float rmv = snrm[ii], rvv = snrv[ii], wv = snw[ii], bv = snb[ii];
#pragma unroll
      for (int i = 0; i < EPW; i++) {
        float x = wi_t[wave][ii][i];
        float mu = msm0 * mean_[i] + msm1 * rmv;
        float va = vsm0 * var_[i] + vsm1 * rvv + 1e-5f;
        wi_t[wave][ii][i] = (x - mu) * rsqrtf(va) * wv + bv;
      }
    }
  }
  __syncthreads();

  // ---- layer 1: 265 -> 64 (o = lane) ----
  float acc[EPW] = {};
  for (int kk = 0; kk < 66; ++kk) {
    float4 v0 = *(const float4*)&wi_t[wave][4 * kk + 0][0];
    float4 v1 = *(const float4*)&wi_t[wave][4 * kk + 1][0];
    float4 v2 = *(const float4*)&wi_t[wave][4 * kk + 2][0];
    float4 v3 = *(const float4*)&wi_t[wave][4 * kk + 3][0];
    float w0 = W1[(4 * kk + 0) * 64 + lane];
    float w1 = W1[(4 * kk + 1) * 64 + lane];
    float w2 = W1[(4 * kk + 2) * 64 + lane];
    float w3 = W1[(4 * kk + 3) * 64 + lane];
    acc[0] = fmaf(v3.x, w3, fmaf(v2.x, w2, fmaf(v1.x, w1, fmaf(v0.x, w0, acc[0]))));
    acc[1] = fmaf(v3.y, w3, fmaf(v2.y, w2, fmaf(v1.y, w1, fmaf(v0.y, w0, acc[1]))));
    acc[2] = fmaf(v3.z, w3, fmaf(v2.z, w2, fmaf(v1.z, w1, fmaf(v0.z, w0, acc[2]))));
    acc[3] = fmaf(v3.w, w3, fmaf(v2.w, w2, fmaf(v1.w, w1, fmaf(v0.w, w0, acc[3]))));
  }
  {
    float4 v = *(const float4*)&wi_t[wave][264][0];
    float w = W1[264 * 64 + lane];
    acc[0] = fmaf(v.x, w, acc[0]); acc[1] = fmaf(v.y, w, acc[1]);
    acc[2] = fmaf(v.z, w, acc[2]); acc[3] = fmaf(v.w, w, acc[3]);
  }
  const float is265 = 1.0f / sqrtf(265.0f);
#pragma unroll
  for (int i = 0; i < EPW; i++) hA[wave][lane][i] = silu_f(acc[i] * is265);
  __syncthreads();

  // ---- layer 2: 64 -> 64 ----
#pragma unroll
  for (int i = 0; i < EPW; i++) acc[i] = 0.f;
  for (int kk = 0; kk < 16; ++kk) {
    float4 v0 = *(const float4*)&hA[wave][4 * kk + 0][0];
    float4 v1 = *(const float4*)&hA[wave][4 * kk + 1][0];
    float4 v2 = *(const float4*)&hA[wave][4 * kk + 2][0];
    float4 v3 = *(const float4*)&hA[wave][4 * kk + 3][0];
    float w0 = W2[(4 * kk + 0) * 64 + lane];
    float w1 = W2[(4 * kk + 1) * 64 + lane];
    float w2 = W2[(4 * kk + 2) * 64 + lane];
    float w3 = W2[(4 * kk + 3) * 64 + lane];
    acc[0] = fmaf(v3.x, w3, fmaf(v2.x, w2, fmaf(v1.x, w1, fmaf(v0.x, w0, acc[0]))));
    acc[1] = fmaf(v3.y, w3, fmaf(v2.y, w2, fmaf(v1.y, w1, fmaf(v0.y, w0, acc[1]))));
    acc[2] = fmaf(v3.z, w3, fmaf(v2.z, w2, fmaf(v1.z, w1, fmaf(v0.z, w0, acc[2]))));
    acc[3] = fmaf(v3.w, w3, fmaf(v2.w, w2, fmaf(v1.w, w1, fmaf(v0.w, w0, acc[3]))));
  }
#pragma unroll
  for (int i = 0; i < EPW; i++) hB[wave][lane][i] = silu_f(acc[i] * 0.125f);
  __syncthreads();

  // ---- layer 3: 64 -> 64 ----
#pragma unroll
  for (int i = 0; i < EPW; i++) acc[i] = 0.f;
  for (int kk = 0; kk < 16; ++kk) {
    float4 v0 = *(const float4*)&hB[wave][4 * kk + 0][0];
    float4 v1 = *(const float4*)&hB[wave][4 * kk + 1][0];
    float4 v2 = *(const float4*)&hB[wave][4 * kk + 2][0];
    float4 v3 = *(const float4*)&hB[wave][4 * kk + 3][0];
    float w0 = W3[(4 * kk + 0) * 64 + lane];
    float w1 = W3[(4 * kk + 1) * 64 + lane];
    float w2 = W3[(4 * kk + 2) * 64 + lane];
    float w3 = W3[(4 * kk + 3) * 64 + lane];
    acc[0] = fmaf(v3.x, w3, fmaf(v2.x, w2, fmaf(v1.x, w1, fmaf(v0.x, w0, acc[0]))));
    acc[1] = fmaf(v3.y, w3, fmaf(v2.y, w2, fmaf(v1.y, w1, fmaf(v0.y, w0, acc[1]))));
    acc[2] = fmaf(v3.z, w3, fmaf(v2.z, w2, fmaf(v1.z, w1, fmaf(v0.z, w0, acc[2]))));
    acc[3] = fmaf(v3.w, w3, fmaf(v2.w, w2, fmaf(v1.w, w1, fmaf(v0.w, w0, acc[3]))));
  }
  __syncthreads();   // hA free to overwrite after this
#pragma unroll
  for (int i = 0; i < EPW; i++) hA[wave][lane][i] = silu_f(acc[i] * 0.125f);
  __syncthreads();

  const float isq3 = 1.0f / sqrtf(3.0f);

  // ---- layer 4 half A (j = 0..3 -> w0, w1) + scatter out0a/out1a ----
  {
    float t4[EPW][4];
#pragma unroll
    for (int i = 0; i < EPW; i++)
#pragma unroll
      for (int j = 0; j < 4; j++) t4[i][j] = 0.f;
    for (int k = 0; k < 64; ++k) {
      float4 hv = *(const float4*)&hA[wave][k][0];
      float hvv[4] = { hv.x, hv.y, hv.z, hv.w };
      float wj[4];
#pragma unroll
      for (int j = 0; j < 4; j++) wj[j] = W4[k * 512 + j * 64 + lane];
#pragma unroll
      for (int i = 0; i < EPW; i++)
#pragma unroll
        for (int j = 0; j < 4; j++) t4[i][j] = fmaf(hvv[i], wj[j], t4[i][j]);
    }
#pragma unroll
    for (int i = 0; i < EPW; i++) {
      if (!valid[i]) continue;
      float se0 = su[(size_t)snd[i] * 128 + lane];
      float se1 = su[(size_t)snd[i] * 128 + 64 + lane];
      float w0a = t4[i][0] * 0.125f, w0b = t4[i][1] * 0.125f;
      float w1a = t4[i][2] * 0.125f, w1b = t4[i][3] * 0.125f;
      float* pM0 = M0 + (size_t)rcv[i] * 256;
      atomicAdd(pM0 + lane,      w0a * se0 * y0v[i]);
      atomicAdd(pM0 + 64 + lane, w0b * se1 * y0v[i]);
      float s0 = w1a * se0, s1v = w1b * se1;
#pragma unroll
      for (int d = 0; d < 3; d++) {
        float* pM1 = M1 + ((size_t)rcv[i] * 3 + d) * 256;
        atomicAdd(pM1 + lane,      s0  * y1v[i][d]);
        atomicAdd(pM1 + 64 + lane, s1v * y1v[i][d]);
      }
    }
  }

  // ---- layer 4 half B (j = 4..7 -> w2, w3) + scatter out0b/out1b ----
  {
    float t4[EPW][4];
#pragma unroll
    for (int i = 0; i < EPW; i++)
#pragma unroll
      for (int j = 0; j < 4; j++) t4[i][j] = 0.f;
    for (int k = 0; k < 64; ++k) {
      float4 hv = *(const float4*)&hA[wave][k][0];
      float hvv[4] = { hv.x, hv.y, hv.z, hv.w };
      float wj[4];
#pragma unroll
      for (int j = 0; j < 4; j++) wj[j] = W4[k * 512 + (4 + j) * 64 + lane];
#pragma unroll
      for (int i = 0; i < EPW; i++)
#pragma unroll
        for (int j = 0; j < 4; j++) t4[i][j] = fmaf(hvv[i], wj[j], t4[i][j]);
    }
#pragma unroll
    for (int i = 0; i < EPW; i++) {
      if (!valid[i]) continue;
      float ve0[3], ve1[3];
#pragma unroll
      for (int d = 0; d < 3; d++) {
        ve0[d] = vu[((size_t)snd[i] * 3 + d) * 128 + lane];
        ve1[d] = vu[((size_t)snd[i] * 3 + d) * 128 + 64 + lane];
      }
      float w2a = t4[i][0] * 0.125f, w2b = t4[i][1] * 0.125f;
      float w3a = t4[i][2] * 0.125f, w3b = t4[i][3] * 0.125f;
      float dot0 = ve0[0] * y1v[i][0] + ve0[1] * y1v[i][1] + ve0[2] * y1v[i][2];
      float dot1 = ve1[0] * y1v[i][0] + ve1[1] * y1v[i][1] + ve1[2] * y1v[i][2];
      float* pM0 = M0 + (size_t)rcv[i] * 256;
      atomicAdd(pM0 + 128 + lane, w3a * dot0 * isq3);
      atomicAdd(pM0 + 192 + lane, w3b * dot1 * isq3);
#pragma unroll
      for (int d = 0; d < 3; d++) {
        float* pM1 = M1 + ((size_t)rcv[i] * 3 + d) * 256;
        atomicAdd(pM1 + 128 + lane, w2a * ve0[d] * y0v[i]);
        atomicAdd(pM1 + 192 + lane, w2b * ve1[d] * y0v[i]);
      }
    }
  }
}

// ---------------------------------------------------------------- out kernel
__global__ __launch_bounds__(128)
void out_kernel(const float* __restrict__ M0, const float* __restrict__ M1,
                const float* __restrict__ Wo0, const float* __restrict__ Wo1,
                float* __restrict__ out, int N)
{
  __shared__ __align__(16) float sM0[4][256];
  __shared__ __align__(16) float sM1[4][3][256];
  const int o = threadIdx.x;
  const int n0 = blockIdx.x * 4;
#pragma unroll
  for (int i = 0; i < 4; i++) {
    int n = n0 + i; if (n >= N) n = N - 1;
#pragma unroll
    for (int q = 0; q < 2; q++)
      sM0[i][o + 128 * q] = M0[(size_t)n * 256 + o + 128 * q];
#pragma unroll
    for (int d = 0; d < 3; d++)
#pragma unroll
      for (int q = 0; q < 2; q++)
        sM1[i][d][o + 128 * q] = M1[((size_t)n * 3 + d) * 256 + o + 128 * q];
  }
  __syncthreads();
  float a0[4] = {}, a1[4][3] = {};
  for (int uu = 0; uu < 64; ++uu) {
    float w0[4], w1[4];
#pragma unroll
    for (int j = 0; j < 4; j++) {
      w0[j] = Wo0[(4 * uu + j) * 128 + o];
      w1[j] = Wo1[(4 * uu + j) * 128 + o];
    }
#pragma unroll
    for (int i = 0; i < 4; i++) {
      float4 m0v = *(const float4*)&sM0[i][4 * uu];
      a0[i] = fmaf(m0v.w, w0[3], fmaf(m0v.z, w0[2], fmaf(m0v.y, w0[1], fmaf(m0v.x, w0[0], a0[i]))));
#pragma unroll
      for (int d = 0; d < 3; d++) {
        float4 m1v = *(const float4*)&sM1[i][d][4 * uu];
        a1[i][d] = fmaf(m1v.w, w1[3], fmaf(m1v.z, w1[2], fmaf(m1v.y, w1[1], fmaf(m1v.x, w1[0], a1[i][d]))));
      }
    }
  }
  const float sc = 1.0f / 256.0f;   // (1/sqrt(256)) / AVG_NEIGH
#pragma unroll
  for (int i = 0; i < 4; i++) {
    int n = n0 + i;
    if (n < N) {
      float4 r;
      r.x = a0[i] * sc; r.y = a1[i][0] * sc; r.z = a1[i][1] * sc; r.w = a1[i][2] * sc;
      *(float4*)(out + ((size_t)n * 128 + o) * 4) = r;
    }
  }
}

// ---------------------------------------------------------------- launcher
extern "C" void kernel_launch(void* const* d_in, const int* in_sizes, int n_in,
                              void* d_out, int out_size, void* d_ws, size_t ws_size,
                              hipStream_t stream)
{
  const float* nf   = (const float*)d_in[0];
  const float* eattr= (const float*)d_in[1];
  const float* elen = (const float*)d_in[2];
  const float* tdif = (const float*)d_in[3];
  const float* lens = (const float*)d_in[4];
  const int*   eidx = (const int*)  d_in[5];
  const float* Ws   = (const float*)d_in[6];
  const float* Wu0  = (const float*)d_in[7];
  const float* Wu1  = (const float*)d_in[8];
  const float* snw  = (const float*)d_in[9];
  const float* snb  = (const float*)d_in[10];
  const float* snmw = (const float*)d_in[11];
  const float* snvw = (const float*)d_in[12];
  const float* snrm = (const float*)d_in[13];
  const float* snrv = (const float*)d_in[14];
  const float* W1   = (const float*)d_in[15];
  const float* W2   = (const float*)d_in[16];
  const float* W3   = (const float*)d_in[17];
  const float* W4   = (const float*)d_in[18];
  const float* Wo0  = (const float*)d_in[19];
  const float* Wo1  = (const float*)d_in[20];

  const int N = in_sizes[0] / 512;
  const int E = in_sizes[1] / 4;

  float* ws = (float*)d_ws;
  float* ns = ws;                         // N*128
  float* su = ws + (size_t)128 * N;       // N*128
  float* vu = ws + (size_t)256 * N;       // N*3*128
  float* M0 = ws + (size_t)640 * N;       // N*256
  float* M1 = ws + (size_t)896 * N;       // N*3*256

  hipMemsetAsync(M0, 0, (size_t)1024 * N * sizeof(float), stream);

  node_kernel<<<dim3((N + 3) / 4), dim3(64), 0, stream>>>(nf, Ws, Wu0, Wu1, ns, su, vu, N);
  edge_kernel<<<dim3((E + WPB * EPW - 1) / (WPB * EPW)), dim3(256), 0, stream>>>(
      eattr, elen, tdif, lens, eidx, snw, snb, snmw, snvw, snrm, snrv,
      W1, W2, W3, W4, ns, su, vu, M0, M1, E);
  out_kernel<<<dim3((N + 3) / 4), dim3(128), 0, stream>>>(M0, M1, Wo0, Wo1, (float*)d_out, N);
}

// Round 2
// 694.299 us; speedup vs baseline: 1.0576x; 1.0576x over previous
//
#include <hip/hip_runtime.h>
#include <hip/hip_bf16.h>
#include <math.h>

// Round 2: edge MLP on bf16 MFMA (16x16x32), fp32 scatter unchanged.
// Block = 128 threads (2 waves), 32 edges. Each wave owns 16 edges (one M-tile).
// Weights pre-swizzled to B-fragment layout (bf16) in workspace by prep_weights.

#define PI_F 3.14159265358979323846f

typedef short  short8 __attribute__((ext_vector_type(8)));
typedef short  short4v __attribute__((ext_vector_type(4)));
typedef float  f32x4 __attribute__((ext_vector_type(4)));

static __device__ __forceinline__ float silu_f(float x) {
  return x / (1.0f + __expf(-x));
}
static __device__ __forceinline__ short f2bf(float x) {
  __hip_bfloat16 h = __float2bfloat16(x);
  return *reinterpret_cast<short*>(&h);
}
static __device__ __forceinline__ float bf2f(short s) {
  __hip_bfloat16 h = *reinterpret_cast<__hip_bfloat16*>(&s);
  return __bfloat162float(h);
}

// ---------------------------------------------------------------- node kernel
__global__ __launch_bounds__(64)
void node_kernel(const float* __restrict__ nf,
                 const float* __restrict__ Ws,
                 const float* __restrict__ Wu0,
                 const float* __restrict__ Wu1,
                 float* __restrict__ ns, float* __restrict__ su,
                 float* __restrict__ vu, int N)
{
  const int lane = threadIdx.x;
  const int n0 = blockIdx.x * 4;
  float a_ns[4][2] = {}, a_su[4][2] = {}, a_vu[4][3][2] = {};
  const float* row[4];
#pragma unroll
  for (int i = 0; i < 4; i++) {
    int n = n0 + i; if (n >= N) n = N - 1;
    row[i] = nf + (size_t)n * 512;
  }
  for (int u = 0; u < 128; ++u) {
    float ws0 = Ws[u * 128 + lane],  ws1 = Ws[u * 128 + 64 + lane];
    float wa0 = Wu0[u * 128 + lane], wa1 = Wu0[u * 128 + 64 + lane];
    float wb0 = Wu1[u * 128 + lane], wb1 = Wu1[u * 128 + 64 + lane];
#pragma unroll
    for (int i = 0; i < 4; i++) {
      float s = row[i][u];
      a_ns[i][0] = fmaf(s, ws0, a_ns[i][0]); a_ns[i][1] = fmaf(s, ws1, a_ns[i][1]);
      a_su[i][0] = fmaf(s, wa0, a_su[i][0]); a_su[i][1] = fmaf(s, wa1, a_su[i][1]);
      float vx = row[i][128 + u * 3 + 0];
      float vy = row[i][128 + u * 3 + 1];
      float vz = row[i][128 + u * 3 + 2];
      a_vu[i][0][0] = fmaf(vx, wb0, a_vu[i][0][0]); a_vu[i][0][1] = fmaf(vx, wb1, a_vu[i][0][1]);
      a_vu[i][1][0] = fmaf(vy, wb0, a_vu[i][1][0]); a_vu[i][1][1] = fmaf(vy, wb1, a_vu[i][1][1]);
      a_vu[i][2][0] = fmaf(vz, wb0, a_vu[i][2][0]); a_vu[i][2][1] = fmaf(vz, wb1, a_vu[i][2][1]);
    }
  }
  const float inv = 1.0f / sqrtf(128.0f);
#pragma unroll
  for (int i = 0; i < 4; i++) {
    int n = n0 + i;
    if (n >= N) break;
    ns[(size_t)n * 128 + lane]      = a_ns[i][0] * inv;
    ns[(size_t)n * 128 + 64 + lane] = a_ns[i][1] * inv;
    su[(size_t)n * 128 + lane]      = a_su[i][0] * inv;
    su[(size_t)n * 128 + 64 + lane] = a_su[i][1] * inv;
#pragma unroll
    for (int d = 0; d < 3; d++) {
      vu[((size_t)n * 3 + d) * 128 + lane]      = a_vu[i][d][0] * inv;
      vu[((size_t)n * 3 + d) * 128 + 64 + lane] = a_vu[i][d][1] * inv;
    }
  }
}

// ---------------------------------------------------------------- prep weights
// B-fragment layout for mfma_f32_16x16x32_bf16:
//   lane holds col n = nt*16 + (lane&15), k = kk*32 + (lane>>4)*8 + i, i=0..7.
// frag ids: L1: kk*4+nt (36) | L2: 36+kk*4+nt (8) | L3: 44+.. (8) | L4: 52+kk*32+nt (64)
__global__ __launch_bounds__(256)
void prep_weights(const float* __restrict__ W1, const float* __restrict__ W2,
                  const float* __restrict__ W3, const float* __restrict__ W4,
                  short* __restrict__ frags)
{
  int t = blockIdx.x * 256 + threadIdx.x;
  if (t >= 116 * 64) return;
  int frag = t >> 6, lane = t & 63;
  const float* W; int K, Nout, kk, nt; float scale;
  if (frag < 36)      { int f = frag;      W = W1; K = 265; Nout = 64;  kk = f >> 2; nt = f & 3;  scale = 1.0f / sqrtf(265.0f); }
  else if (frag < 44) { int f = frag - 36; W = W2; K = 64;  Nout = 64;  kk = f >> 2; nt = f & 3;  scale = 0.125f; }
  else if (frag < 52) { int f = frag - 44; W = W3; K = 64;  Nout = 64;  kk = f >> 2; nt = f & 3;  scale = 0.125f; }
  else                { int f = frag - 52; W = W4; K = 64;  Nout = 512; kk = f >> 5; nt = f & 31; scale = 0.125f; }
  int n = nt * 16 + (lane & 15);
  short* out = frags + ((size_t)(frag * 64 + lane)) * 8;
#pragma unroll
  for (int i = 0; i < 8; i++) {
    int k = kk * 32 + ((lane >> 4) << 3) + i;
    float v = (k < K) ? W[(size_t)k * Nout + n] * scale : 0.0f;
    out[i] = f2bf(v);
  }
}

// ---------------------------------------------------------------- edge kernel
#define EB 32   // edges per block (2 waves x 16)

__global__ __launch_bounds__(128)
void edge_kernel(const float* __restrict__ eattr,
                 const float* __restrict__ elen,
                 const float* __restrict__ tdif,
                 const float* __restrict__ lens,
                 const int*   __restrict__ eidx,
                 const float* __restrict__ snw, const float* __restrict__ snb,
                 const float* __restrict__ snmw, const float* __restrict__ snvw,
                 const float* __restrict__ snrm, const float* __restrict__ snrv,
                 const float* __restrict__ ns, const float* __restrict__ su,
                 const float* __restrict__ vu,
                 const short* __restrict__ frags,
                 float* __restrict__ M0, float* __restrict__ M1,
                 int E)
{
  __shared__ __align__(16) short wi[EB][296];   // bf16, K padded to 288
  __shared__ __align__(16) short hA[EB][72];
  __shared__ __align__(16) short hB[EB][72];
  __shared__ int   snd_s[EB], rcv_s[EB];
  __shared__ float y_s[EB][4];

  const int tid  = threadIdx.x;
  const int lane = tid & 63;
  const int w    = tid >> 6;         // wave 0/1

  // ======== build wi (raw bf16) + per-edge stats ========
  {
    const int el = tid >> 2, s = tid & 3;      // 4 threads per edge
    const int e  = blockIdx.x * EB + el;
    const int snd = eidx[e], rcv = eidx[E + e];
    if (s == 0) { snd_s[el] = snd; rcv_s[el] = rcv; }
    y_s[el][s] = eattr[e * 4 + s];
    const float r = elen[e], tt = tdif[e], ln = lens[e];
    float u = r * 0.2f;
    float u2 = u * u, u4 = u2 * u2, u5 = u4 * u;
    float cc = 1.0f - 21.0f * u5 + 35.0f * u5 * u - 15.0f * u5 * u2;
    const float cut = (u < 1.0f) ? cc : 0.0f;
    const float pref = sqrtf(0.4f);

    float s1 = 0.f, s2 = 0.f;
    for (int j = 0; j < 18; ++j) {             // chunk c = s + 4*j, k = 4c..4c+3
      int c = s + 4 * j;
      if (c >= 72) break;
      int k0 = c * 4;
      float v[4];
      if (k0 < 128) {
        float4 g = *(const float4*)&ns[(size_t)snd * 128 + k0];
        v[0] = g.x * cut; v[1] = g.y * cut; v[2] = g.z * cut; v[3] = g.w * cut;
      } else if (k0 < 256) {
        float4 g = *(const float4*)&ns[(size_t)rcv * 128 + (k0 - 128)];
        v[0] = g.x * cut; v[1] = g.y * cut; v[2] = g.z * cut; v[3] = g.w * cut;
      } else if (k0 < 264) {
#pragma unroll
        for (int i = 0; i < 4; i++) {
          float kk = (float)(k0 - 255 + i) * (PI_F / 5.0f);
          v[i] = pref * __sinf(kk * r) / r * __expf(-kk * kk * tt) * cut;
        }
      } else if (k0 == 264) {
        v[0] = ln * cut; v[1] = 0.f; v[2] = 0.f; v[3] = 0.f;
      } else {
        v[0] = v[1] = v[2] = v[3] = 0.f;
      }
#pragma unroll
      for (int i = 0; i < 4; i++)
        if (k0 + i < 265) { s1 += v[i]; s2 += v[i] * v[i]; }
      short4v b;
#pragma unroll
      for (int i = 0; i < 4; i++) b[i] = f2bf(v[i]);
      *(short4v*)&wi[el][k0] = b;
    }
    // reduce over the 4 threads of this edge
    s1 += __shfl_xor(s1, 1); s1 += __shfl_xor(s1, 2);
    s2 += __shfl_xor(s2, 1); s2 += __shfl_xor(s2, 2);
    const float mean = s1 * (1.0f / 265.0f);
    const float var  = (s2 - s1 * mean) * (1.0f / 264.0f);   // ddof=1
    const float msm0 = 1.0f / (1.0f + __expf(snmw[1] - snmw[0])), msm1 = 1.0f - msm0;
    const float vsm0 = 1.0f / (1.0f + __expf(snvw[1] - snvw[0])), vsm1 = 1.0f - vsm0;

    // normalize in place (same thread owns same chunks)
    for (int j = 0; j < 17; ++j) {
      int c = s + 4 * j;
      if (c >= 67) break;
      int k0 = c * 4;
      float4 rm = *(const float4*)&snrm[k0 <= 260 ? k0 : 260];  // guard, real load below
      float4 rv, wv, bv;
      if (k0 + 3 < 265) {
        rm = *(const float4*)&snrm[k0]; rv = *(const float4*)&snrv[k0];
        wv = *(const float4*)&snw[k0];  bv = *(const float4*)&snb[k0];
      }
      short4v b = *(short4v*)&wi[el][k0];
#pragma unroll
      for (int i = 0; i < 4; i++) {
        int k = k0 + i;
        if (k < 265) {
          float rmv, rvv, wvv, bvv;
          if (k0 + 3 < 265) {
            rmv = ((const float*)&rm)[i]; rvv = ((const float*)&rv)[i];
            wvv = ((const float*)&wv)[i]; bvv = ((const float*)&bv)[i];
          } else {
            rmv = snrm[k]; rvv = snrv[k]; wvv = snw[k]; bvv = snb[k];
          }
          float x  = bf2f(b[i]);
          float mu = msm0 * mean + msm1 * rmv;
          float va = vsm0 * var + vsm1 * rvv + 1e-5f;
          b[i] = f2bf((x - mu) * rsqrtf(va) * wvv + bvv);
        }
      }
      *(short4v*)&wi[el][k0] = b;
    }
  }
  __syncthreads();

  // ======== MFMA layers ========
  const short8* F = (const short8*)frags;
  const int arow = w * 16 + (lane & 15);       // A-frag row (edge)
  const int kgrp = (lane >> 4) << 3;           // k sub-offset within 32-chunk

  // ---- layer 1: 288 -> 64 ----
  f32x4 A0 = {0,0,0,0}, A1 = {0,0,0,0}, A2 = {0,0,0,0}, A3 = {0,0,0,0};
#pragma unroll
  for (int kk = 0; kk < 9; ++kk) {
    short8 a = *(const short8*)&wi[arow][kk * 32 + kgrp];
    A0 = __builtin_amdgcn_mfma_f32_16x16x32_bf16(a, F[(kk * 4 + 0) * 64 + lane], A0, 0, 0, 0);
    A1 = __builtin_amdgcn_mfma_f32_16x16x32_bf16(a, F[(kk * 4 + 1) * 64 + lane], A1, 0, 0, 0);
    A2 = __builtin_amdgcn_mfma_f32_16x16x32_bf16(a, F[(kk * 4 + 2) * 64 + lane], A2, 0, 0, 0);
    A3 = __builtin_amdgcn_mfma_f32_16x16x32_bf16(a, F[(kk * 4 + 3) * 64 + lane], A3, 0, 0, 0);
  }
#pragma unroll
  for (int rr = 0; rr < 4; ++rr) {
    int er = w * 16 + ((lane >> 4) << 2) + rr;
    hA[er][ 0 + (lane & 15)] = f2bf(silu_f(A0[rr]));
    hA[er][16 + (lane & 15)] = f2bf(silu_f(A1[rr]));
    hA[er][32 + (lane & 15)] = f2bf(silu_f(A2[rr]));
    hA[er][48 + (lane & 15)] = f2bf(silu_f(A3[rr]));
  }
  __syncthreads();

  // ---- layer 2: 64 -> 64 ----
  A0 = A1 = A2 = A3 = (f32x4){0,0,0,0};
#pragma unroll
  for (int kk = 0; kk < 2; ++kk) {
    short8 a = *(const short8*)&hA[arow][kk * 32 + kgrp];
    A0 = __builtin_amdgcn_mfma_f32_16x16x32_bf16(a, F[(36 + kk * 4 + 0) * 64 + lane], A0, 0, 0, 0);
    A1 = __builtin_amdgcn_mfma_f32_16x16x32_bf16(a, F[(36 + kk * 4 + 1) * 64 + lane], A1, 0, 0, 0);
    A2 = __builtin_amdgcn_mfma_f32_16x16x32_bf16(a, F[(36 + kk * 4 + 2) * 64 + lane], A2, 0, 0, 0);
    A3 = __builtin_amdgcn_mfma_f32_16x16x32_bf16(a, F[(36 + kk * 4 + 3) * 64 + lane], A3, 0, 0, 0);
  }
#pragma unroll
  for (int rr = 0; rr < 4; ++rr) {
    int er = w * 16 + ((lane >> 4) << 2) + rr;
    hB[er][ 0 + (lane & 15)] = f2bf(silu_f(A0[rr]));
    hB[er][16 + (lane & 15)] = f2bf(silu_f(A1[rr]));
    hB[er][32 + (lane & 15)] = f2bf(silu_f(A2[rr]));
    hB[er][48 + (lane & 15)] = f2bf(silu_f(A3[rr]));
  }
  __syncthreads();

  // ---- layer 3: 64 -> 64 (reads hB, writes hA) ----
  A0 = A1 = A2 = A3 = (f32x4){0,0,0,0};
#pragma unroll
  for (int kk = 0; kk < 2; ++kk) {
    short8 a = *(const short8*)&hB[arow][kk * 32 + kgrp];
    A0 = __builtin_amdgcn_mfma_f32_16x16x32_bf16(a, F[(44 + kk * 4 + 0) * 64 + lane], A0, 0, 0, 0);
    A1 = __builtin_amdgcn_mfma_f32_16x16x32_bf16(a, F[(44 + kk * 4 + 1) * 64 + lane], A1, 0, 0, 0);
    A2 = __builtin_amdgcn_mfma_f32_16x16x32_bf16(a, F[(44 + kk * 4 + 2) * 64 + lane], A2, 0, 0, 0);
    A3 = __builtin_amdgcn_mfma_f32_16x16x32_bf16(a, F[(44 + kk * 4 + 3) * 64 + lane], A3, 0, 0, 0);
  }
  __syncthreads();
#pragma unroll
  for (int rr = 0; rr < 4; ++rr) {
    int er = w * 16 + ((lane >> 4) << 2) + rr;
    hA[er][ 0 + (lane & 15)] = f2bf(silu_f(A0[rr]));
    hA[er][16 + (lane & 15)] = f2bf(silu_f(A1[rr]));
    hA[er][32 + (lane & 15)] = f2bf(silu_f(A2[rr]));
    hA[er][48 + (lane & 15)] = f2bf(silu_f(A3[rr]));
  }
  __syncthreads();

  // ---- per-lane edge meta for scatter ----
  int   sndr[4], rcvr[4];
  float y0r[4], y1r[4][3];
#pragma unroll
  for (int rr = 0; rr < 4; ++rr) {
    int ee = w * 16 + ((lane >> 4) << 2) + rr;
    sndr[rr] = snd_s[ee]; rcvr[rr] = rcv_s[ee];
    y0r[rr] = y_s[ee][0];
    y1r[rr][0] = y_s[ee][1]; y1r[rr][1] = y_s[ee][2]; y1r[rr][2] = y_s[ee][3];
  }
  const float isq3 = 1.0f / sqrtf(3.0f);

  // A-frags for layer 4 (reused across all t)
  short8 a40 = *(const short8*)&hA[arow][ 0 + kgrp];
  short8 a41 = *(const short8*)&hA[arow][32 + kgrp];

  // ---- layer 4: 64 -> 512 in 8 tiles of 16 cols x 4 chunks, fused scatter ----
#pragma unroll
  for (int t = 0; t < 8; ++t) {
    f32x4 W0 = {0,0,0,0}, W1t = {0,0,0,0}, W2t = {0,0,0,0}, W3t = {0,0,0,0};
    W0  = __builtin_amdgcn_mfma_f32_16x16x32_bf16(a40, F[(52 + 0 * 32 + ( 0 + t)) * 64 + lane], W0,  0, 0, 0);
    W0  = __builtin_amdgcn_mfma_f32_16x16x32_bf16(a41, F[(52 + 1 * 32 + ( 0 + t)) * 64 + lane], W0,  0, 0, 0);
    W1t = __builtin_amdgcn_mfma_f32_16x16x32_bf16(a40, F[(52 + 0 * 32 + ( 8 + t)) * 64 + lane], W1t, 0, 0, 0);
    W1t = __builtin_amdgcn_mfma_f32_16x16x32_bf16(a41, F[(52 + 1 * 32 + ( 8 + t)) * 64 + lane], W1t, 0, 0, 0);
    W2t = __builtin_amdgcn_mfma_f32_16x16x32_bf16(a40, F[(52 + 0 * 32 + (16 + t)) * 64 + lane], W2t, 0, 0, 0);
    W2t = __builtin_amdgcn_mfma_f32_16x16x32_bf16(a41, F[(52 + 1 * 32 + (16 + t)) * 64 + lane], W2t, 0, 0, 0);
    W3t = __builtin_amdgcn_mfma_f32_16x16x32_bf16(a40, F[(52 + 0 * 32 + (24 + t)) * 64 + lane], W3t, 0, 0, 0);
    W3t = __builtin_amdgcn_mfma_f32_16x16x32_bf16(a41, F[(52 + 1 * 32 + (24 + t)) * 64 + lane], W3t, 0, 0, 0);

    const int uu = t * 16 + (lane & 15);
#pragma unroll
    for (int rr = 0; rr < 4; ++rr) {
      float se  = su[(size_t)sndr[rr] * 128 + uu];
      float ve0 = vu[((size_t)sndr[rr] * 3 + 0) * 128 + uu];
      float ve1 = vu[((size_t)sndr[rr] * 3 + 1) * 128 + uu];
      float ve2 = vu[((size_t)sndr[rr] * 3 + 2) * 128 + uu];
      float dotv = ve0 * y1r[rr][0] + ve1 * y1r[rr][1] + ve2 * y1r[rr][2];
      float* p0 = M0 + (size_t)rcvr[rr] * 256;
      atomicAdd(p0 + uu,        W0[rr] * se * y0r[rr]);
      atomicAdd(p0 + 128 + uu,  W3t[rr] * dotv * isq3);
      float s1v = W1t[rr] * se;
      float v2  = W2t[rr] * y0r[rr];
      atomicAdd(M1 + ((size_t)rcvr[rr] * 3 + 0) * 256 + uu, s1v * y1r[rr][0]);
      atomicAdd(M1 + ((size_t)rcvr[rr] * 3 + 1) * 256 + uu, s1v * y1r[rr][1]);
      atomicAdd(M1 + ((size_t)rcvr[rr] * 3 + 2) * 256 + uu, s1v * y1r[rr][2]);
      atomicAdd(M1 + ((size_t)rcvr[rr] * 3 + 0) * 256 + 128 + uu, v2 * ve0);
      atomicAdd(M1 + ((size_t)rcvr[rr] * 3 + 1) * 256 + 128 + uu, v2 * ve1);
      atomicAdd(M1 + ((size_t)rcvr[rr] * 3 + 2) * 256 + 128 + uu, v2 * ve2);
    }
  }
}

// ---------------------------------------------------------------- out kernel
__global__ __launch_bounds__(128)
void out_kernel(const float* __restrict__ M0, const float* __restrict__ M1,
                const float* __restrict__ Wo0, const float* __restrict__ Wo1,
                float* __restrict__ out, int N)
{
  __shared__ __align__(16) float sM0[4][256];
  __shared__ __align__(16) float sM1[4][3][256];
  const int o = threadIdx.x;
  const int n0 = blockIdx.x * 4;
#pragma unroll
  for (int i = 0; i < 4; i++) {
    int n = n0 + i; if (n >= N) n = N - 1;
#pragma unroll
    for (int q = 0; q < 2; q++)
      sM0[i][o + 128 * q] = M0[(size_t)n * 256 + o + 128 * q];
#pragma unroll
    for (int d = 0; d < 3; d++)
#pragma unroll
      for (int q = 0; q < 2; q++)
        sM1[i][d][o + 128 * q] = M1[((size_t)n * 3 + d) * 256 + o + 128 * q];
  }
  __syncthreads();
  float a0[4] = {}, a1[4][3] = {};
  for (int uu = 0; uu < 64; ++uu) {
    float w0[4], w1[4];
#pragma unroll
    for (int j = 0; j < 4; j++) {
      w0[j] = Wo0[(4 * uu + j) * 128 + o];
      w1[j] = Wo1[(4 * uu + j) * 128 + o];
    }
#pragma unroll
    for (int i = 0; i < 4; i++) {
      float4 m0v = *(const float4*)&sM0[i][4 * uu];
      a0[i] = fmaf(m0v.w, w0[3], fmaf(m0v.z, w0[2], fmaf(m0v.y, w0[1], fmaf(m0v.x, w0[0], a0[i]))));
#pragma unroll
      for (int d = 0; d < 3; d++) {
        float4 m1v = *(const float4*)&sM1[i][d][4 * uu];
        a1[i][d] = fmaf(m1v.w, w1[3], fmaf(m1v.z, w1[2], fmaf(m1v.y, w1[1], fmaf(m1v.x, w1[0], a1[i][d]))));
      }
    }
  }
  const float sc = 1.0f / 256.0f;   // (1/sqrt(256)) / AVG_NEIGH
#pragma unroll
  for (int i = 0; i < 4; i++) {
    int n = n0 + i;
    if (n < N) {
      float4 r;
      r.x = a0[i] * sc; r.y = a1[i][0] * sc; r.z = a1[i][1] * sc; r.w = a1[i][2] * sc;
      *(float4*)(out + ((size_t)n * 128 + o) * 4) = r;
    }
  }
}

// ---------------------------------------------------------------- launcher
extern "C" void kernel_launch(void* const* d_in, const int* in_sizes, int n_in,
                              void* d_out, int out_size, void* d_ws, size_t ws_size,
                              hipStream_t stream)
{
  const float* nf   = (const float*)d_in[0];
  const float* eattr= (const float*)d_in[1];
  const float* elen = (const float*)d_in[2];
  const float* tdif = (const float*)d_in[3];
  const float* lens = (const float*)d_in[4];
  const int*   eidx = (const int*)  d_in[5];
  const float* Ws   = (const float*)d_in[6];
  const float* Wu0  = (const float*)d_in[7];
  const float* Wu1  = (const float*)d_in[8];
  const float* snw  = (const float*)d_in[9];
  const float* snb  = (const float*)d_in[10];
  const float* snmw = (const float*)d_in[11];
  const float* snvw = (const float*)d_in[12];
  const float* snrm = (const float*)d_in[13];
  const float* snrv = (const float*)d_in[14];
  const float* W1   = (const float*)d_in[15];
  const float* W2   = (const float*)d_in[16];
  const float* W3   = (const float*)d_in[17];
  const float* W4   = (const float*)d_in[18];
  const float* Wo0  = (const float*)d_in[19];
  const float* Wo1  = (const float*)d_in[20];

  const int N = in_sizes[0] / 512;
  const int E = in_sizes[1] / 4;

  float* ws = (float*)d_ws;
  float* ns = ws;                         // N*128
  float* su = ws + (size_t)128 * N;       // N*128
  float* vu = ws + (size_t)256 * N;       // N*3*128
  float* M0 = ws + (size_t)640 * N;       // N*256
  float* M1 = ws + (size_t)896 * N;       // N*3*256
  short* frags = (short*)(ws + (size_t)1664 * N);   // 116*64*8 bf16 = 118 KB

  hipMemsetAsync(M0, 0, (size_t)1024 * N * sizeof(float), stream);

  prep_weights<<<dim3((116 * 64 + 255) / 256), dim3(256), 0, stream>>>(W1, W2, W3, W4, frags);
  node_kernel<<<dim3((N + 3) / 4), dim3(64), 0, stream>>>(nf, Ws, Wu0, Wu1, ns, su, vu, N);
  edge_kernel<<<dim3((E + EB - 1) / EB), dim3(128), 0, stream>>>(
      eattr, elen, tdif, lens, eidx, snw, snb, snmw, snvw, snrm, snrv,
      ns, su, vu, frags, M0, M1, E);
  out_kernel<<<dim3((N + 3) / 4), dim3(128), 0, stream>>>(M0, M1, Wo0, Wo1, (float*)d_out, N);
}

// Round 3
// 488.348 us; speedup vs baseline: 1.5036x; 1.4217x over previous
//
#include <hip/hip_runtime.h>
#include <hip/hip_bf16.h>
#include <math.h>

// Round 3: kill the atomic scatter.
//   sort edges by receiver (hist/scan/scatter CSR) ->
//   edge_mlp writes per-edge tpw (512 bf16, cols packed w0w1w2w3) in sorted order ->
//   gather_kernel: one block per node owns M0/M1, zero atomics.
// tpw buffer chunked over ws_size.

#define PI_F 3.14159265358979323846f

typedef short  short8 __attribute__((ext_vector_type(8)));
typedef short  short4v __attribute__((ext_vector_type(4)));
typedef float  f32x4 __attribute__((ext_vector_type(4)));

static __device__ __forceinline__ float silu_f(float x) {
  return x / (1.0f + __expf(-x));
}
static __device__ __forceinline__ short f2bf(float x) {
  __hip_bfloat16 h = __float2bfloat16(x);
  return *reinterpret_cast<short*>(&h);
}
static __device__ __forceinline__ float bf2f(short s) {
  __hip_bfloat16 h = *reinterpret_cast<__hip_bfloat16*>(&s);
  return __bfloat162float(h);
}

// ---------------------------------------------------------------- node kernel
__global__ __launch_bounds__(64)
void node_kernel(const float* __restrict__ nf,
                 const float* __restrict__ Ws,
                 const float* __restrict__ Wu0,
                 const float* __restrict__ Wu1,
                 float* __restrict__ ns, float* __restrict__ su,
                 float* __restrict__ vu, int N)
{
  const int lane = threadIdx.x;
  const int n0 = blockIdx.x * 4;
  float a_ns[4][2] = {}, a_su[4][2] = {}, a_vu[4][3][2] = {};
  const float* row[4];
#pragma unroll
  for (int i = 0; i < 4; i++) {
    int n = n0 + i; if (n >= N) n = N - 1;
    row[i] = nf + (size_t)n * 512;
  }
  for (int u = 0; u < 128; ++u) {
    float ws0 = Ws[u * 128 + lane],  ws1 = Ws[u * 128 + 64 + lane];
    float wa0 = Wu0[u * 128 + lane], wa1 = Wu0[u * 128 + 64 + lane];
    float wb0 = Wu1[u * 128 + lane], wb1 = Wu1[u * 128 + 64 + lane];
#pragma unroll
    for (int i = 0; i < 4; i++) {
      float s = row[i][u];
      a_ns[i][0] = fmaf(s, ws0, a_ns[i][0]); a_ns[i][1] = fmaf(s, ws1, a_ns[i][1]);
      a_su[i][0] = fmaf(s, wa0, a_su[i][0]); a_su[i][1] = fmaf(s, wa1, a_su[i][1]);
      float vx = row[i][128 + u * 3 + 0];
      float vy = row[i][128 + u * 3 + 1];
      float vz = row[i][128 + u * 3 + 2];
      a_vu[i][0][0] = fmaf(vx, wb0, a_vu[i][0][0]); a_vu[i][0][1] = fmaf(vx, wb1, a_vu[i][0][1]);
      a_vu[i][1][0] = fmaf(vy, wb0, a_vu[i][1][0]); a_vu[i][1][1] = fmaf(vy, wb1, a_vu[i][1][1]);
      a_vu[i][2][0] = fmaf(vz, wb0, a_vu[i][2][0]); a_vu[i][2][1] = fmaf(vz, wb1, a_vu[i][2][1]);
    }
  }
  const float inv = 1.0f / sqrtf(128.0f);
#pragma unroll
  for (int i = 0; i < 4; i++) {
    int n = n0 + i;
    if (n >= N) break;
    ns[(size_t)n * 128 + lane]      = a_ns[i][0] * inv;
    ns[(size_t)n * 128 + 64 + lane] = a_ns[i][1] * inv;
    su[(size_t)n * 128 + lane]      = a_su[i][0] * inv;
    su[(size_t)n * 128 + 64 + lane] = a_su[i][1] * inv;
#pragma unroll
    for (int d = 0; d < 3; d++) {
      vu[((size_t)n * 3 + d) * 128 + lane]      = a_vu[i][d][0] * inv;
      vu[((size_t)n * 3 + d) * 128 + 64 + lane] = a_vu[i][d][1] * inv;
    }
  }
}

// ---------------------------------------------------------------- prep weights
// B-fragment layout for mfma_f32_16x16x32_bf16:
//   lane holds col n = nt*16 + (lane&15), k = kk*32 + (lane>>4)*8 + i, i=0..7.
// frag ids: L1: kk*4+nt (36) | L2: 36+.. (8) | L3: 44+.. (8) | L4: 52+kk*32+nt (64)
// W4 cols 384..511 (w3, nt>=24) additionally carry 1/sqrt(3).
__global__ __launch_bounds__(256)
void prep_weights(const float* __restrict__ W1, const float* __restrict__ W2,
                  const float* __restrict__ W3, const float* __restrict__ W4,
                  short* __restrict__ frags)
{
  int t = blockIdx.x * 256 + threadIdx.x;
  if (t >= 116 * 64) return;
  int frag = t >> 6, lane = t & 63;
  const float* W; int K, Nout, kk, nt; float scale;
  if (frag < 36)      { int f = frag;      W = W1; K = 265; Nout = 64;  kk = f >> 2; nt = f & 3;  scale = 1.0f / sqrtf(265.0f); }
  else if (frag < 44) { int f = frag - 36; W = W2; K = 64;  Nout = 64;  kk = f >> 2; nt = f & 3;  scale = 0.125f; }
  else if (frag < 52) { int f = frag - 44; W = W3; K = 64;  Nout = 64;  kk = f >> 2; nt = f & 3;  scale = 0.125f; }
  else                { int f = frag - 52; W = W4; K = 64;  Nout = 512; kk = f >> 5; nt = f & 31;
                        scale = 0.125f * ((nt >= 24) ? 0.57735026918962576f : 1.0f); }
  int n = nt * 16 + (lane & 15);
  short* out = frags + ((size_t)(frag * 64 + lane)) * 8;
#pragma unroll
  for (int i = 0; i < 8; i++) {
    int k = kk * 32 + ((lane >> 4) << 3) + i;
    float v = (k < K) ? W[(size_t)k * Nout + n] * scale : 0.0f;
    out[i] = f2bf(v);
  }
}

// ---------------------------------------------------------------- sort kernels
__global__ __launch_bounds__(256)
void hist_kernel(const int* __restrict__ eidx, int* __restrict__ cnt, int E)
{
  int e = blockIdx.x * 256 + threadIdx.x;
  if (e < E) atomicAdd(&cnt[eidx[E + e]], 1);
}

__global__ __launch_bounds__(1024)
void scan_kernel(const int* __restrict__ cnt, int* __restrict__ rs,
                 int* __restrict__ cursor, int N)
{
  __shared__ int buf[1024];
  __shared__ int carry;
  if (threadIdx.x == 0) { carry = 0; rs[0] = 0; }
  __syncthreads();
  for (int base = 0; base < N; base += 1024) {
    int i = base + (int)threadIdx.x;
    int v = (i < N) ? cnt[i] : 0;
    buf[threadIdx.x] = v;
    __syncthreads();
    for (int off = 1; off < 1024; off <<= 1) {
      int t = (threadIdx.x >= (unsigned)off) ? buf[threadIdx.x - off] : 0;
      __syncthreads();
      buf[threadIdx.x] += t;
      __syncthreads();
    }
    int inc = buf[threadIdx.x] + carry;
    if (i < N) { rs[i + 1] = inc; cursor[i] = inc - v; }
    __syncthreads();
    if (threadIdx.x == 1023) carry = inc;
    __syncthreads();
  }
}

__global__ __launch_bounds__(256)
void scatter_kernel(const int* __restrict__ eidx, int* __restrict__ cursor,
                    int* __restrict__ perm, int E)
{
  int e = blockIdx.x * 256 + threadIdx.x;
  if (e < E) {
    int r = eidx[E + e];
    int pos = atomicAdd(&cursor[r], 1);
    perm[pos] = e;
  }
}

// ---------------------------------------------------------------- edge MLP
#define EB 32   // edges per block (2 waves x 16)

__global__ __launch_bounds__(128)
void edge_mlp(const float* __restrict__ elen,
              const float* __restrict__ tdif,
              const float* __restrict__ lens,
              const int*   __restrict__ eidx,
              const float* __restrict__ snw, const float* __restrict__ snb,
              const float* __restrict__ snmw, const float* __restrict__ snvw,
              const float* __restrict__ snrm, const float* __restrict__ snrv,
              const float* __restrict__ ns,
              const short* __restrict__ frags,
              const int*   __restrict__ perm,
              short* __restrict__ tpw,
              int e_lo, int E)
{
  __shared__ __align__(16) short wi[EB][296];   // bf16, K padded to 288
  __shared__ __align__(16) short hA[EB][72];
  __shared__ __align__(16) short hB[EB][72];

  const int tid  = threadIdx.x;
  const int lane = tid & 63;
  const int w    = tid >> 6;

  // ======== build wi (bf16) + per-edge stats ========
  {
    const int el = tid >> 2, s = tid & 3;      // 4 threads per edge
    int gi = e_lo + blockIdx.x * EB + el;
    if (gi >= E) gi = E - 1;                   // pad rows replicate last edge
    const int e = perm[gi];
    const int snd = eidx[e], rcv = eidx[E + e];
    const float r = elen[e], tt = tdif[e], ln = lens[e];
    float u = r * 0.2f;
    float u2 = u * u, u4 = u2 * u2, u5 = u4 * u;
    float cc = 1.0f - 21.0f * u5 + 35.0f * u5 * u - 15.0f * u5 * u2;
    const float cut = (u < 1.0f) ? cc : 0.0f;
    const float pref = sqrtf(0.4f);

    float s1 = 0.f, s2 = 0.f;
    for (int j = 0; j < 18; ++j) {             // chunk c = s + 4*j, k = 4c..4c+3
      int c = s + 4 * j;
      if (c >= 72) break;
      int k0 = c * 4;
      float v[4];
      if (k0 < 128) {
        float4 g = *(const float4*)&ns[(size_t)snd * 128 + k0];
        v[0] = g.x * cut; v[1] = g.y * cut; v[2] = g.z * cut; v[3] = g.w * cut;
      } else if (k0 < 256) {
        float4 g = *(const float4*)&ns[(size_t)rcv * 128 + (k0 - 128)];
        v[0] = g.x * cut; v[1] = g.y * cut; v[2] = g.z * cut; v[3] = g.w * cut;
      } else if (k0 < 264) {
#pragma unroll
        for (int i = 0; i < 4; i++) {
          float kk = (float)(k0 - 255 + i) * (PI_F / 5.0f);
          v[i] = pref * __sinf(kk * r) / r * __expf(-kk * kk * tt) * cut;
        }
      } else if (k0 == 264) {
        v[0] = ln * cut; v[1] = 0.f; v[2] = 0.f; v[3] = 0.f;
      } else {
        v[0] = v[1] = v[2] = v[3] = 0.f;
      }
#pragma unroll
      for (int i = 0; i < 4; i++)
        if (k0 + i < 265) { s1 += v[i]; s2 += v[i] * v[i]; }
      short4v b;
#pragma unroll
      for (int i = 0; i < 4; i++) b[i] = f2bf(v[i]);
      *(short4v*)&wi[el][k0] = b;
    }
    // reduce over the 4 threads of this edge
    s1 += __shfl_xor(s1, 1); s1 += __shfl_xor(s1, 2);
    s2 += __shfl_xor(s2, 1); s2 += __shfl_xor(s2, 2);
    const float mean = s1 * (1.0f / 265.0f);
    const float var  = (s2 - s1 * mean) * (1.0f / 264.0f);   // ddof=1
    const float msm0 = 1.0f / (1.0f + __expf(snmw[1] - snmw[0])), msm1 = 1.0f - msm0;
    const float vsm0 = 1.0f / (1.0f + __expf(snvw[1] - snvw[0])), vsm1 = 1.0f - vsm0;

    for (int j = 0; j < 17; ++j) {
      int c = s + 4 * j;
      if (c >= 67) break;
      int k0 = c * 4;
      short4v b = *(short4v*)&wi[el][k0];
#pragma unroll
      for (int i = 0; i < 4; i++) {
        int k = k0 + i;
        if (k < 265) {
          float rmv = snrm[k], rvv = snrv[k], wvv = snw[k], bvv = snb[k];
          float x  = bf2f(b[i]);
          float mu = msm0 * mean + msm1 * rmv;
          float va = vsm0 * var + vsm1 * rvv + 1e-5f;
          b[i] = f2bf((x - mu) * rsqrtf(va) * wvv + bvv);
        }
      }
      *(short4v*)&wi[el][k0] = b;
    }
  }
  __syncthreads();

  // ======== MFMA layers ========
  const short8* F = (const short8*)frags;
  const int arow = w * 16 + (lane & 15);
  const int kgrp = (lane >> 4) << 3;

  // ---- layer 1: 288 -> 64 ----
  f32x4 A0 = {0,0,0,0}, A1 = {0,0,0,0}, A2 = {0,0,0,0}, A3 = {0,0,0,0};
#pragma unroll
  for (int kk = 0; kk < 9; ++kk) {
    short8 a = *(const short8*)&wi[arow][kk * 32 + kgrp];
    A0 = __builtin_amdgcn_mfma_f32_16x16x32_bf16(a, F[(kk * 4 + 0) * 64 + lane], A0, 0, 0, 0);
    A1 = __builtin_amdgcn_mfma_f32_16x16x32_bf16(a, F[(kk * 4 + 1) * 64 + lane], A1, 0, 0, 0);
    A2 = __builtin_amdgcn_mfma_f32_16x16x32_bf16(a, F[(kk * 4 + 2) * 64 + lane], A2, 0, 0, 0);
    A3 = __builtin_amdgcn_mfma_f32_16x16x32_bf16(a, F[(kk * 4 + 3) * 64 + lane], A3, 0, 0, 0);
  }
#pragma unroll
  for (int rr = 0; rr < 4; ++rr) {
    int er = w * 16 + ((lane >> 4) << 2) + rr;
    hA[er][ 0 + (lane & 15)] = f2bf(silu_f(A0[rr]));
    hA[er][16 + (lane & 15)] = f2bf(silu_f(A1[rr]));
    hA[er][32 + (lane & 15)] = f2bf(silu_f(A2[rr]));
    hA[er][48 + (lane & 15)] = f2bf(silu_f(A3[rr]));
  }
  __syncthreads();

  // ---- layer 2: 64 -> 64 ----
  A0 = A1 = A2 = A3 = (f32x4){0,0,0,0};
#pragma unroll
  for (int kk = 0; kk < 2; ++kk) {
    short8 a = *(const short8*)&hA[arow][kk * 32 + kgrp];
    A0 = __builtin_amdgcn_mfma_f32_16x16x32_bf16(a, F[(36 + kk * 4 + 0) * 64 + lane], A0, 0, 0, 0);
    A1 = __builtin_amdgcn_mfma_f32_16x16x32_bf16(a, F[(36 + kk * 4 + 1) * 64 + lane], A1, 0, 0, 0);
    A2 = __builtin_amdgcn_mfma_f32_16x16x32_bf16(a, F[(36 + kk * 4 + 2) * 64 + lane], A2, 0, 0, 0);
    A3 = __builtin_amdgcn_mfma_f32_16x16x32_bf16(a, F[(36 + kk * 4 + 3) * 64 + lane], A3, 0, 0, 0);
  }
#pragma unroll
  for (int rr = 0; rr < 4; ++rr) {
    int er = w * 16 + ((lane >> 4) << 2) + rr;
    hB[er][ 0 + (lane & 15)] = f2bf(silu_f(A0[rr]));
    hB[er][16 + (lane & 15)] = f2bf(silu_f(A1[rr]));
    hB[er][32 + (lane & 15)] = f2bf(silu_f(A2[rr]));
    hB[er][48 + (lane & 15)] = f2bf(silu_f(A3[rr]));
  }
  __syncthreads();

  // ---- layer 3: 64 -> 64 ----
  A0 = A1 = A2 = A3 = (f32x4){0,0,0,0};
#pragma unroll
  for (int kk = 0; kk < 2; ++kk) {
    short8 a = *(const short8*)&hB[arow][kk * 32 + kgrp];
    A0 = __builtin_amdgcn_mfma_f32_16x16x32_bf16(a, F[(44 + kk * 4 + 0) * 64 + lane], A0, 0, 0, 0);
    A1 = __builtin_amdgcn_mfma_f32_16x16x32_bf16(a, F[(44 + kk * 4 + 1) * 64 + lane], A1, 0, 0, 0);
    A2 = __builtin_amdgcn_mfma_f32_16x16x32_bf16(a, F[(44 + kk * 4 + 2) * 64 + lane], A2, 0, 0, 0);
    A3 = __builtin_amdgcn_mfma_f32_16x16x32_bf16(a, F[(44 + kk * 4 + 3) * 64 + lane], A3, 0, 0, 0);
  }
  __syncthreads();
#pragma unroll
  for (int rr = 0; rr < 4; ++rr) {
    int er = w * 16 + ((lane >> 4) << 2) + rr;
    hA[er][ 0 + (lane & 15)] = f2bf(silu_f(A0[rr]));
    hA[er][16 + (lane & 15)] = f2bf(silu_f(A1[rr]));
    hA[er][32 + (lane & 15)] = f2bf(silu_f(A2[rr]));
    hA[er][48 + (lane & 15)] = f2bf(silu_f(A3[rr]));
  }
  __syncthreads();

  // A-frags for layer 4
  short8 a40 = *(const short8*)&hA[arow][ 0 + kgrp];
  short8 a41 = *(const short8*)&hA[arow][32 + kgrp];
  const int rowbase = blockIdx.x * EB + w * 16 + ((lane >> 4) << 2);

  // ---- layer 4: 64 -> 512, write tpw (col-packed w0,w1,w2,w3) ----
#pragma unroll
  for (int t = 0; t < 8; ++t) {
    f32x4 W0 = {0,0,0,0}, W1t = {0,0,0,0}, W2t = {0,0,0,0}, W3t = {0,0,0,0};
    W0  = __builtin_amdgcn_mfma_f32_16x16x32_bf16(a40, F[(52 + 0 * 32 + ( 0 + t)) * 64 + lane], W0,  0, 0, 0);
    W0  = __builtin_amdgcn_mfma_f32_16x16x32_bf16(a41, F[(52 + 1 * 32 + ( 0 + t)) * 64 + lane], W0,  0, 0, 0);
    W1t = __builtin_amdgcn_mfma_f32_16x16x32_bf16(a40, F[(52 + 0 * 32 + ( 8 + t)) * 64 + lane], W1t, 0, 0, 0);
    W1t = __builtin_amdgcn_mfma_f32_16x16x32_bf16(a41, F[(52 + 1 * 32 + ( 8 + t)) * 64 + lane], W1t, 0, 0, 0);
    W2t = __builtin_amdgcn_mfma_f32_16x16x32_bf16(a40, F[(52 + 0 * 32 + (16 + t)) * 64 + lane], W2t, 0, 0, 0);
    W2t = __builtin_amdgcn_mfma_f32_16x16x32_bf16(a41, F[(52 + 1 * 32 + (16 + t)) * 64 + lane], W2t, 0, 0, 0);
    W3t = __builtin_amdgcn_mfma_f32_16x16x32_bf16(a40, F[(52 + 0 * 32 + (24 + t)) * 64 + lane], W3t, 0, 0, 0);
    W3t = __builtin_amdgcn_mfma_f32_16x16x32_bf16(a41, F[(52 + 1 * 32 + (24 + t)) * 64 + lane], W3t, 0, 0, 0);

    const int uu = t * 16 + (lane & 15);
#pragma unroll
    for (int rr = 0; rr < 4; ++rr) {
      short4v pk;
      pk[0] = f2bf(W0[rr]); pk[1] = f2bf(W1t[rr]);
      pk[2] = f2bf(W2t[rr]); pk[3] = f2bf(W3t[rr]);
      *(short4v*)(tpw + (size_t)(rowbase + rr) * 512 + uu * 4) = pk;
    }
  }
}

// ---------------------------------------------------------------- gather kernel
// one block per node; owns M0[n]/M1[n] exclusively -> plain read-add-write.
__global__ __launch_bounds__(128)
void gather_kernel(const int* __restrict__ rs, const int* __restrict__ perm,
                   const int* __restrict__ eidx, const float* __restrict__ eattr,
                   const float* __restrict__ su, const float* __restrict__ vu,
                   const short* __restrict__ tpw,
                   float* __restrict__ M0, float* __restrict__ M1,
                   int e_lo, int e_hi, int E)
{
  const int n = blockIdx.x;
  const int o = threadIdx.x;
  int lo = rs[n], hi = rs[n + 1];
  if (lo < e_lo) lo = e_lo;
  if (hi > e_hi) hi = e_hi;
  if (lo >= hi) return;

  float a0 = 0.f, a1 = 0.f;
  float b0 = 0.f, b1 = 0.f, b2 = 0.f;
  float c0 = 0.f, c1 = 0.f, c2 = 0.f;

  for (int idx = lo; idx < hi; ++idx) {
    const int e = perm[idx];                       // uniform
    const int snd = eidx[e];                       // uniform
    const float y0  = eattr[e * 4 + 0];
    const float y10 = eattr[e * 4 + 1];
    const float y11 = eattr[e * 4 + 2];
    const float y12 = eattr[e * 4 + 3];
    const float se = su[(size_t)snd * 128 + o];
    const float v0 = vu[((size_t)snd * 3 + 0) * 128 + o];
    const float v1 = vu[((size_t)snd * 3 + 1) * 128 + o];
    const float v2 = vu[((size_t)snd * 3 + 2) * 128 + o];
    short4v pk = *(const short4v*)(tpw + (size_t)(idx - e_lo) * 512 + o * 4);
    const float w0 = bf2f(pk[0]), w1 = bf2f(pk[1]);
    const float w2 = bf2f(pk[2]), w3 = bf2f(pk[3]);
    const float dot = v0 * y10 + v1 * y11 + v2 * y12;
    a0 = fmaf(w0 * se, y0, a0);
    a1 = fmaf(w3, dot, a1);                        // isq3 folded into w3
    const float s1v = w1 * se;
    b0 = fmaf(s1v, y10, b0); b1 = fmaf(s1v, y11, b1); b2 = fmaf(s1v, y12, b2);
    const float vv = w2 * y0;
    c0 = fmaf(vv, v0, c0); c1 = fmaf(vv, v1, c1); c2 = fmaf(vv, v2, c2);
  }
  float* p0 = M0 + (size_t)n * 256;
  p0[o] += a0; p0[128 + o] += a1;
  float* p1 = M1 + (size_t)n * 3 * 256;
  p1[0 * 256 + o] += b0; p1[1 * 256 + o] += b1; p1[2 * 256 + o] += b2;
  p1[0 * 256 + 128 + o] += c0; p1[1 * 256 + 128 + o] += c1; p1[2 * 256 + 128 + o] += c2;
}

// ---------------------------------------------------------------- out kernel
__global__ __launch_bounds__(128)
void out_kernel(const float* __restrict__ M0, const float* __restrict__ M1,
                const float* __restrict__ Wo0, const float* __restrict__ Wo1,
                float* __restrict__ out, int N)
{
  __shared__ __align__(16) float sM0[4][256];
  __shared__ __align__(16) float sM1[4][3][256];
  const int o = threadIdx.x;
  const int n0 = blockIdx.x * 4;
#pragma unroll
  for (int i = 0; i < 4; i++) {
    int n = n0 + i; if (n >= N) n = N - 1;
#pragma unroll
    for (int q = 0; q < 2; q++)
      sM0[i][o + 128 * q] = M0[(size_t)n * 256 + o + 128 * q];
#pragma unroll
    for (int d = 0; d < 3; d++)
#pragma unroll
      for (int q = 0; q < 2; q++)
        sM1[i][d][o + 128 * q] = M1[((size_t)n * 3 + d) * 256 + o + 128 * q];
  }
  __syncthreads();
  float a0[4] = {}, a1[4][3] = {};
  for (int uu = 0; uu < 64; ++uu) {
    float w0[4], w1[4];
#pragma unroll
    for (int j = 0; j < 4; j++) {
      w0[j] = Wo0[(4 * uu + j) * 128 + o];
      w1[j] = Wo1[(4 * uu + j) * 128 + o];
    }
#pragma unroll
    for (int i = 0; i < 4; i++) {
      float4 m0v = *(const float4*)&sM0[i][4 * uu];
      a0[i] = fmaf(m0v.w, w0[3], fmaf(m0v.z, w0[2], fmaf(m0v.y, w0[1], fmaf(m0v.x, w0[0], a0[i]))));
#pragma unroll
      for (int d = 0; d < 3; d++) {
        float4 m1v = *(const float4*)&sM1[i][d][4 * uu];
        a1[i][d] = fmaf(m1v.w, w1[3], fmaf(m1v.z, w1[2], fmaf(m1v.y, w1[1], fmaf(m1v.x, w1[0], a1[i][d]))));
      }
    }
  }
  const float sc = 1.0f / 256.0f;   // (1/sqrt(256)) / AVG_NEIGH
#pragma unroll
  for (int i = 0; i < 4; i++) {
    int n = n0 + i;
    if (n < N) {
      float4 r;
      r.x = a0[i] * sc; r.y = a1[i][0] * sc; r.z = a1[i][1] * sc; r.w = a1[i][2] * sc;
      *(float4*)(out + ((size_t)n * 128 + o) * 4) = r;
    }
  }
}

// ---------------------------------------------------------------- launcher
extern "C" void kernel_launch(void* const* d_in, const int* in_sizes, int n_in,
                              void* d_out, int out_size, void* d_ws, size_t ws_size,
                              hipStream_t stream)
{
  const float* nf   = (const float*)d_in[0];
  const float* eattr= (const float*)d_in[1];
  const float* elen = (const float*)d_in[2];
  const float* tdif = (const float*)d_in[3];
  const float* lens = (const float*)d_in[4];
  const int*   eidx = (const int*)  d_in[5];
  const float* Ws   = (const float*)d_in[6];
  const float* Wu0  = (const float*)d_in[7];
  const float* Wu1  = (const float*)d_in[8];
  const float* snw  = (const float*)d_in[9];
  const float* snb  = (const float*)d_in[10];
  const float* snmw = (const float*)d_in[11];
  const float* snvw = (const float*)d_in[12];
  const float* snrm = (const float*)d_in[13];
  const float* snrv = (const float*)d_in[14];
  const float* W1   = (const float*)d_in[15];
  const float* W2   = (const float*)d_in[16];
  const float* W3   = (const float*)d_in[17];
  const float* W4   = (const float*)d_in[18];
  const float* Wo0  = (const float*)d_in[19];
  const float* Wo1  = (const float*)d_in[20];

  const int N = in_sizes[0] / 512;
  const int E = in_sizes[1] / 4;

  float* ws = (float*)d_ws;
  float* ns = ws;                         // N*128
  float* su = ws + (size_t)128 * N;       // N*128
  float* vu = ws + (size_t)256 * N;       // N*3*128
  float* M0 = ws + (size_t)640 * N;       // N*256
  float* M1 = ws + (size_t)896 * N;       // N*3*256
  short* frags = (short*)(ws + (size_t)1664 * N);   // 116*64*8 bf16
  int* cnt    = (int*)(frags + 116 * 64 * 8);
  int* rs     = cnt + N;                  // N+1
  int* cursor = rs + N + 1;               // N
  int* perm   = cursor + N;               // E
  size_t used = (size_t)((char*)(perm + E) - (char*)d_ws);
  used = (used + 255) & ~(size_t)255;
  short* tpw = (short*)((char*)d_ws + used);
  size_t avail = (ws_size > used) ? (ws_size - used) : 0;

  long long chunk = (long long)(avail / 1024) & ~31LL;   // edges per chunk (1KB each)
  long long Eup = ((long long)E + 31) & ~31LL;
  if (chunk > Eup) chunk = Eup;
  if (chunk < 32)  chunk = 32;            // last-resort (assumes ws covers it)

  hipMemsetAsync(M0, 0, (size_t)1024 * N * sizeof(float), stream);
  hipMemsetAsync(cnt, 0, (size_t)N * sizeof(int), stream);

  prep_weights<<<dim3((116 * 64 + 255) / 256), dim3(256), 0, stream>>>(W1, W2, W3, W4, frags);
  node_kernel<<<dim3((N + 3) / 4), dim3(64), 0, stream>>>(nf, Ws, Wu0, Wu1, ns, su, vu, N);
  hist_kernel<<<dim3((E + 255) / 256), dim3(256), 0, stream>>>(eidx, cnt, E);
  scan_kernel<<<dim3(1), dim3(1024), 0, stream>>>(cnt, rs, cursor, N);
  scatter_kernel<<<dim3((E + 255) / 256), dim3(256), 0, stream>>>(eidx, cursor, perm, E);

  for (long long lo = 0; lo < E; lo += chunk) {
    int n_e = (int)(((long long)E - lo < chunk) ? ((long long)E - lo) : chunk);
    int blocks = (n_e + EB - 1) / EB;
    edge_mlp<<<dim3(blocks), dim3(128), 0, stream>>>(
        elen, tdif, lens, eidx, snw, snb, snmw, snvw, snrm, snrv,
        ns, frags, perm, tpw, (int)lo, E);
    gather_kernel<<<dim3(N), dim3(128), 0, stream>>>(
        rs, perm, eidx, eattr, su, vu, tpw, M0, M1, (int)lo, (int)(lo + n_e), E);
  }

  out_kernel<<<dim3((N + 3) / 4), dim3(128), 0, stream>>>(M0, M1, Wo0, Wo1, (float*)d_out, N);
}